// Round 1
// 371.533 us; speedup vs baseline: 1.1029x; 1.1029x over previous
//
#include <hip/hip_runtime.h>
#include <hip/hip_bf16.h>

// GCN 2-hop SGConv, W-first restructure:
//   (A^2 x) W + b  ==  A^2 (x W) + b   (linear commutes with aggregation)
// Pipeline: ELL fill (4-pass, XCD-write-local) -> k_gemm0: h0=bf16(xW) via
// split-bf16 MFMA (f32-quality input rounding) -> hop1: h1=Ahat@h0 (bf16
// 256B-row gather, was f32 512B rows -> halves hop1 past-L2 bytes) ->
// hop2: out = Ahat@h1 + b.
// Hops run at ~3.5 TB/s past-L2 random-gather service ceiling (R4/R6, 3
// structures); FETCH ~= NXCD * footprint (compulsory per-XCD), so the only
// lever is footprint: 51.2MB f32 -> 25.6MB bf16 for hop1.
// h0 staged in d_out (dead before hop2's final write) -> ws stays 51.7 MB
// (52 MB proven safe in R2).
// ELL width 64 (P(deg>64)~1e-18, drop-guard). cnt[] doubles as degree;
// dinv recomputed in-hop as rsqrtf(cnt+1) (cnt is 400KB, L2-resident).
// Runtime dtype detection: flags[0]=f32 storage, flags[1]=int64 edges.

#define DFEAT 128
#define ELLW 64

typedef __attribute__((ext_vector_type(8))) short short8;
typedef __attribute__((ext_vector_type(4))) float f32x4;

__device__ __forceinline__ float bf2f(unsigned short u) {
    union { unsigned int i; float f; } t;
    t.i = ((unsigned int)u) << 16;
    return t.f;
}

__device__ __forceinline__ unsigned short f2bf(float f) {
    union { float f; unsigned int i; } t;
    t.f = f;
    unsigned int lsb = (t.i >> 16) & 1u;
    t.i += 0x7fffu + lsb;   // round-to-nearest-even
    return (unsigned short)(t.i >> 16);
}

__device__ __forceinline__ void accum8(float* acc, uint4 u, float w) {
    acc[0] += bf2f((unsigned short)(u.x & 0xffffu)) * w;
    acc[1] += bf2f((unsigned short)(u.x >> 16)) * w;
    acc[2] += bf2f((unsigned short)(u.y & 0xffffu)) * w;
    acc[3] += bf2f((unsigned short)(u.y >> 16)) * w;
    acc[4] += bf2f((unsigned short)(u.z & 0xffffu)) * w;
    acc[5] += bf2f((unsigned short)(u.z >> 16)) * w;
    acc[6] += bf2f((unsigned short)(u.w & 0xffffu)) * w;
    acc[7] += bf2f((unsigned short)(u.w >> 16)) * w;
}

// ---- dtype detection ----
__global__ void k_detect(const unsigned short* __restrict__ xs,
                         const int* __restrict__ ei, int* __restrict__ flags) {
    __shared__ int s_f32, s_oddnz;
    if (threadIdx.x == 0) { s_f32 = 0; s_oddnz = 0; }
    __syncthreads();
    int bad = 0;
    for (int i = threadIdx.x; i < 16384; i += 256) {
        unsigned int e = (xs[i] >> 7) & 0xFFu;   // bf16 exponent field
        if (e >= 0xC0u) bad = 1;                 // |v| >= 2^65: impossible for real data
    }
    if (bad) atomicOr(&s_f32, 1);
    int oddnz = 0;
    for (int i = threadIdx.x; i < 4096; i += 256) {
        if (ei[2 * i + 1] != 0) oddnz = 1;       // int32 data has nonzero odd words
    }
    if (oddnz) atomicOr(&s_oddnz, 1);
    __syncthreads();
    if (threadIdx.x == 0) {
        flags[0] = s_f32;
        flags[1] = s_oddnz ? 0 : 1;
    }
}

// ---- ELL fill, 4 passes: block class r owns dst-classes {r, r+4} of 8 ----
// Write working set per XCD ~1.8 MB (< 4 MB L2) -> line-clustered writebacks.
__global__ __launch_bounds__(256) void k_fill_ell(const int* __restrict__ ei, int E, int n,
                                                  const int* __restrict__ flags,
                                                  int* __restrict__ cnt,
                                                  int* __restrict__ ell) {
    int r = blockIdx.x & 3;
    int c = blockIdx.x >> 2;
    int nchunks = gridDim.x >> 2;
    int chunk = (E + nchunks - 1) / nchunks;
    int e0 = c * chunk;
    int e1 = min(E, e0 + chunk);
    int i64 = flags[1];
    float inv8n = 8.0f / (float)n;   // deterministic per-dst class
    for (int e = e0 + (int)threadIdx.x; e < e1; e += 256) {
        int d = i64 ? ei[2 * (E + e)] : ei[E + e];
        int own = min((int)((float)d * inv8n), 7);
        if ((own & 3) != r) continue;
        int s = i64 ? ei[2 * e] : ei[e];
        int pos = atomicAdd(cnt + d, 1);
        if (pos < ELLW) ell[(size_t)d * ELLW + pos] = s;   // overflow guard
    }
}

// ---- W -> MFMA B-frag linear layout (bf16) ----
__global__ void k_prepB(const void* __restrict__ Wraw, const int* __restrict__ flags,
                        unsigned short* __restrict__ Bf) {
    int t = blockIdx.x * 256 + threadIdx.x;  // 2048 total
    if (t >= 2048) return;
    int lane = t & 63;
    int chunk = (t >> 6) & 3;
    int ntile = t >> 8;
    int ncol = ntile * 16 + (lane & 15);
    int k0 = chunk * 32 + (lane >> 4) * 8;
    int isf = flags[0];
    const float* Wf = (const float*)Wraw;
    const unsigned short* Wb = (const unsigned short*)Wraw;
    unsigned short* o = Bf + (size_t)t * 8;
#pragma unroll
    for (int j = 0; j < 8; j++) {
        int idx = (k0 + j) * DFEAT + ncol;
        o[j] = isf ? f2bf(Wf[idx]) : Wb[idx];
    }
}

// ---- k_gemm0: h0 = bf16(x @ W), split-bf16 A operand for f32-quality input ----
// Block = 4 waves = one 16-row M-tile. Coalesced row loads -> hi/lo bf16 LDS
// tiles (pad 136 breaks bank alias) -> 16 MFMA (8 hi + 8 lo) per wave.
__global__ __launch_bounds__(256) void k_gemm0(const void* __restrict__ xraw,
                                               const unsigned short* __restrict__ Bf,
                                               const int* __restrict__ flags,
                                               unsigned short* __restrict__ h0, int n) {
    __shared__ unsigned short thi[16 * 136];
    __shared__ unsigned short tlo[16 * 136];
    int wave = threadIdx.x >> 6;
    int lane = threadIdx.x & 63;
    int g = lane >> 4, c = lane & 15;
    int trow = wave * 4 + g;
    int node = blockIdx.x * 16 + trow;
    int isf = flags[0];

    uint4 ohi = {0, 0, 0, 0}, olo = {0, 0, 0, 0};
    if (node < n) {
        if (isf) {
            const float* xf = (const float*)xraw;
            float4 v0 = *(const float4*)(xf + (size_t)node * DFEAT + c * 8);
            float4 v1 = *(const float4*)(xf + (size_t)node * DFEAT + c * 8 + 4);
            float vv[8] = {v0.x, v0.y, v0.z, v0.w, v1.x, v1.y, v1.z, v1.w};
            unsigned short h[8], l[8];
#pragma unroll
            for (int j = 0; j < 8; j++) {
                h[j] = f2bf(vv[j]);
                l[j] = f2bf(vv[j] - bf2f(h[j]));   // residual -> ~2^-18 input error
            }
            ohi.x = (unsigned int)h[0] | ((unsigned int)h[1] << 16);
            ohi.y = (unsigned int)h[2] | ((unsigned int)h[3] << 16);
            ohi.z = (unsigned int)h[4] | ((unsigned int)h[5] << 16);
            ohi.w = (unsigned int)h[6] | ((unsigned int)h[7] << 16);
            olo.x = (unsigned int)l[0] | ((unsigned int)l[1] << 16);
            olo.y = (unsigned int)l[2] | ((unsigned int)l[3] << 16);
            olo.z = (unsigned int)l[4] | ((unsigned int)l[5] << 16);
            olo.w = (unsigned int)l[6] | ((unsigned int)l[7] << 16);
        } else {
            ohi = *(const uint4*)((const unsigned short*)xraw + (size_t)node * DFEAT + c * 8);
        }
    }
    *(uint4*)(thi + trow * 136 + c * 8) = ohi;
    *(uint4*)(tlo + trow * 136 + c * 8) = olo;
    __syncthreads();

    int m = c, quad = g;
    f32x4 acc2[2];
    acc2[0] = (f32x4){0.f, 0.f, 0.f, 0.f};
    acc2[1] = (f32x4){0.f, 0.f, 0.f, 0.f};
#pragma unroll
    for (int c2 = 0; c2 < 4; c2++) {
        short8 ah = *(const short8*)(thi + m * 136 + c2 * 32 + quad * 8);
        short8 al = *(const short8*)(tlo + m * 136 + c2 * 32 + quad * 8);
#pragma unroll
        for (int t = 0; t < 2; t++) {
            int nt = wave * 2 + t;
            short8 bfr = *(const short8*)(Bf + ((size_t)(nt * 4 + c2) * 64 + lane) * 8);
            acc2[t] = __builtin_amdgcn_mfma_f32_16x16x32_bf16(ah, bfr, acc2[t], 0, 0, 0);
            acc2[t] = __builtin_amdgcn_mfma_f32_16x16x32_bf16(al, bfr, acc2[t], 0, 0, 0);
        }
    }

    // C/D layout: col=lane&15, row=quad*4+reg [learn_hip m89/m91]
#pragma unroll
    for (int t = 0; t < 2; t++) {
        int col = (wave * 2 + t) * 16 + m;
#pragma unroll
        for (int r = 0; r < 4; r++) {
            int grow = blockIdx.x * 16 + quad * 4 + r;
            if (grow < n) h0[(size_t)grow * DFEAT + col] = f2bf(acc2[t][r]);
        }
    }
}

// ---- shared hop body: wave-per-node, bf16 rows, 16 sources in flight ----
__device__ __forceinline__ void hop_accum(const unsigned short* __restrict__ fb,
                                          const int* __restrict__ ell,
                                          const int* __restrict__ cnt,
                                          int node, int lane, float* acc) {
    int g = lane >> 4, c = lane & 15;
    int deg = min(cnt[node], ELLW);
    const int* row = ell + (size_t)node * ELLW;
    float wd = rsqrtf((float)(deg + 1));
#pragma unroll
    for (int j = 0; j < 8; j++) acc[j] = 0.f;

    if (g == 0) {   // self-loop term
        uint4 u = *(const uint4*)(fb + (size_t)node * DFEAT + c * 8);
        accum8(acc, u, wd * wd);
    }
    int last = deg - 1;
    for (int base = 0; base < deg; base += 16) {
        int k0 = base + g, k1 = k0 + 4, k2 = k0 + 8, k3 = k0 + 12;
        int s0 = row[min(k0, last)];
        int s1 = row[min(k1, last)];
        int s2 = row[min(k2, last)];
        int s3 = row[min(k3, last)];
        uint4 u0 = *(const uint4*)(fb + (size_t)s0 * DFEAT + c * 8);
        uint4 u1 = *(const uint4*)(fb + (size_t)s1 * DFEAT + c * 8);
        uint4 u2 = *(const uint4*)(fb + (size_t)s2 * DFEAT + c * 8);
        uint4 u3 = *(const uint4*)(fb + (size_t)s3 * DFEAT + c * 8);
        float w0 = (k0 < deg) ? rsqrtf((float)(cnt[s0] + 1)) * wd : 0.f;
        float w1 = (k1 < deg) ? rsqrtf((float)(cnt[s1] + 1)) * wd : 0.f;
        float w2 = (k2 < deg) ? rsqrtf((float)(cnt[s2] + 1)) * wd : 0.f;
        float w3 = (k3 < deg) ? rsqrtf((float)(cnt[s3] + 1)) * wd : 0.f;
        accum8(acc, u0, w0);
        accum8(acc, u1, w1);
        accum8(acc, u2, w2);
        accum8(acc, u3, w3);
    }
#pragma unroll
    for (int j = 0; j < 8; j++) {
        acc[j] += __shfl_xor(acc[j], 16);
        acc[j] += __shfl_xor(acc[j], 32);
    }
}

// ---- hop1: h1 = Ahat @ h0 (bf16 -> bf16) ----
__global__ __launch_bounds__(256) void k_hop(const unsigned short* __restrict__ src,
                                             const int* __restrict__ ell,
                                             const int* __restrict__ cnt,
                                             unsigned short* __restrict__ outb, int n) {
    int node = blockIdx.x * 4 + (threadIdx.x >> 6);
    if (node >= n) return;
    int lane = threadIdx.x & 63;
    int g = lane >> 4, c = lane & 15;
    float acc[8];
    hop_accum(src, ell, cnt, node, lane, acc);
    if (g == 0) {
        uint4 o;
        o.x = (unsigned int)f2bf(acc[0]) | ((unsigned int)f2bf(acc[1]) << 16);
        o.y = (unsigned int)f2bf(acc[2]) | ((unsigned int)f2bf(acc[3]) << 16);
        o.z = (unsigned int)f2bf(acc[4]) | ((unsigned int)f2bf(acc[5]) << 16);
        o.w = (unsigned int)f2bf(acc[6]) | ((unsigned int)f2bf(acc[7]) << 16);
        *(uint4*)(outb + (size_t)node * DFEAT + c * 8) = o;
    }
}

// ---- hop2: out = Ahat @ h1 + b (bf16 -> out dtype) ----
__global__ __launch_bounds__(256) void k_hop2_out(const unsigned short* __restrict__ src,
                                                  const int* __restrict__ ell,
                                                  const int* __restrict__ cnt,
                                                  const void* __restrict__ braw,
                                                  const int* __restrict__ flags,
                                                  void* __restrict__ outraw, int n) {
    int node = blockIdx.x * 4 + (threadIdx.x >> 6);
    if (node >= n) return;
    int lane = threadIdx.x & 63;
    int g = lane >> 4, c = lane & 15;
    float acc[8];
    hop_accum(src, ell, cnt, node, lane, acc);
    if (g == 0) {
        int isf = flags[0];
        const float* bf32 = (const float*)braw;
        const unsigned short* bb16 = (const unsigned short*)braw;
#pragma unroll
        for (int j = 0; j < 8; j++)
            acc[j] += isf ? bf32[c * 8 + j] : bf2f(bb16[c * 8 + j]);
        if (isf) {
            float* outf = (float*)outraw;
            *(float4*)(outf + (size_t)node * DFEAT + c * 8) =
                (float4){acc[0], acc[1], acc[2], acc[3]};
            *(float4*)(outf + (size_t)node * DFEAT + c * 8 + 4) =
                (float4){acc[4], acc[5], acc[6], acc[7]};
        } else {
            unsigned short* outb = (unsigned short*)outraw;
            uint4 o;
            o.x = (unsigned int)f2bf(acc[0]) | ((unsigned int)f2bf(acc[1]) << 16);
            o.y = (unsigned int)f2bf(acc[2]) | ((unsigned int)f2bf(acc[3]) << 16);
            o.z = (unsigned int)f2bf(acc[4]) | ((unsigned int)f2bf(acc[5]) << 16);
            o.w = (unsigned int)f2bf(acc[6]) | ((unsigned int)f2bf(acc[7]) << 16);
            *(uint4*)(outb + (size_t)node * DFEAT + c * 8) = o;
        }
    }
}

extern "C" void kernel_launch(void* const* d_in, const int* in_sizes, int n_in,
                              void* d_out, int out_size, void* d_ws, size_t ws_size,
                              hipStream_t stream) {
    const void* x = d_in[0];                 // [n,128] f32 or bf16 (detected)
    const int* ei = (const int*)d_in[1];     // [2,E] int32 or int64 (detected)
    const void* W = d_in[2];                 // [128,128]
    const void* b = d_in[3];                 // [128]

    const int n = in_sizes[0] / DFEAT;       // 100000
    const int E = in_sizes[1] / 2;           // 1600000

    // ws layout: ell (n*64 i32, 25.6MB) | h1 (n*128 bf16, 25.6MB) | cnt (n i32)
    // | flags (4 i32) | Bf (16384 bf16)   ~= 51.7 MB
    // h0 = bf16(xW) is staged in d_out (dead before hop2's final write).
    int* ell = (int*)d_ws;
    unsigned short* h1 = (unsigned short*)(ell + (size_t)n * ELLW);
    int* cnt = (int*)(h1 + (size_t)n * DFEAT);
    int* flags = cnt + n;
    unsigned short* Bf = (unsigned short*)(flags + 4);
    unsigned short* h0 = (unsigned short*)d_out;

    hipMemsetAsync(cnt, 0, (size_t)n * sizeof(int), stream);

    k_detect<<<1, 256, 0, stream>>>((const unsigned short*)x, ei, flags);

    // ELL fill: 4 passes x 2048 chunks
    k_fill_ell<<<4 * 2048, 256, 0, stream>>>(ei, E, n, flags, cnt, ell);

    k_prepB<<<8, 256, 0, stream>>>(W, flags, Bf);

    // W-first: h0 = bf16(x @ W)  (split-bf16 A operand)
    k_gemm0<<<(n + 15) / 16, 256, 0, stream>>>(x, Bf, flags, h0, n);

    // hop 1: h1 = Ahat @ h0  (bf16 256B-row gather)
    k_hop<<<(n + 3) / 4, 256, 0, stream>>>(h0, ell, cnt, h1, n);

    // hop 2: out = Ahat @ h1 + b
    k_hop2_out<<<(n + 3) / 4, 256, 0, stream>>>(h1, ell, cnt, b, flags, d_out, n);
}